// Round 6
// baseline (590.988 us; speedup 1.0000x reference)
//
#include <hip/hip_runtime.h>
#include <math.h>

#define L_SPH 7
#define K_RAD 6
#define LK    42          // L*K
#define TPB   256
#define PTPB  64          // pair-kernel block: 1 wave -> 10.75KB LDS
#define RSTR  48          // rbf row stride (floats): 192B = 3x64B sectors.
                          // [0..41]=basis (edge_basis), [42]=x, [43]=env,
                          // [44..46]=normalized dir (edge_pre), [47]=pad.

// ROUND-5 MODEL CORRECTION: per-iteration = 1 poison fill (211us, fixed) +
// edge (238us!) + pair (134us). edge was latency-bound: 42 serial f64-sincos
// per thread at 184 VGPR / 11% occupancy / VALUBusy 30%. This round: one
// thread PER BASIS ELEMENT (nE*42 threads, 1 sincos each) -> small per-thread
// state, high occupancy, latency hidden. Bit-identical arithmetic per element.
// ROUND-4 (sort-by-sender, 1004us, REVERTED): scattered row writes are
// transaction-bound; pair stays in round-3 form (sector-minimal gathers +
// LDS-transpose full-line NT writes).

typedef float f32x4 __attribute__((ext_vector_type(4)));
typedef float f32x2 __attribute__((ext_vector_type(2)));

// ---------------- host-side constants (replicates numpy bisection exactly) ---

struct SBConsts {
    float z[L_SPH][K_RAD];     // Bessel zeros z_{l,n}, rounded to f32 like ref
    float nrm[L_SPH][K_RAD];   // normalizers c_{l,n}, rounded to f32 like ref
    float sphc[L_SPH];         // sqrt((2l+1)/4pi), f32
};

static double host_sph_jn(double r, int l) {
    double j = sin(r) / r;
    if (l == 0) return j;
    double jp = sin(r) / (r * r) - cos(r) / r;
    for (int i = 1; i < l; i++) {
        double t = (2.0 * i + 1.0) / r * jp - j;
        j = jp; jp = t;
    }
    return jp;
}

static SBConsts make_consts() {
    const int L = L_SPH, K = K_RAD;
    double prev[L + K];
    for (int i = 0; i < L + K; i++) prev[i] = (i + 1) * M_PI;
    int plen = L + K;
    double zeros[L_SPH][K_RAD];
    for (int n = 0; n < K; n++) zeros[0][n] = prev[n];
    for (int l = 1; l < L; l++) {
        int m = plen - 1;
        double lo[L + K], hi[L + K], flo[L + K];
        for (int i = 0; i < m; i++) {
            lo[i] = prev[i]; hi[i] = prev[i + 1];
            flo[i] = host_sph_jn(lo[i], l);
        }
        for (int it = 0; it < 100; it++) {
            for (int i = 0; i < m; i++) {
                double mid = 0.5 * (lo[i] + hi[i]);
                double fm  = host_sph_jn(mid, l);
                bool same  = (fm >= 0.0) == (flo[i] >= 0.0);
                if (same) { lo[i] = mid; flo[i] = fm; }
                else      { hi[i] = mid; }
            }
        }
        for (int i = 0; i < m; i++) prev[i] = 0.5 * (lo[i] + hi[i]);
        plen = m;
        for (int n = 0; n < K; n++) zeros[l][n] = prev[n];
    }
    SBConsts c;
    for (int l = 0; l < L; l++) {
        for (int n = 0; n < K; n++) {
            c.z[l][n] = (float)zeros[l][n];
            double j1 = host_sph_jn(zeros[l][n], l + 1);
            c.nrm[l][n] = (float)(1.0 / sqrt(0.5 * j1 * j1));
        }
        c.sphc[l] = (float)sqrt((2.0 * l + 1.0) / (4.0 * M_PI));
    }
    return c;
}

// ---------------- device helpers --------------------------------------------
// f64-evaluate, round once to f32 (proxy for numpy f32 trig; see prior rounds).
// l=0 uses sin() (not sincos) to keep bits identical to the verified kernel.
__device__ __forceinline__ float sin_f32cr(float t) { return (float)sin((double)t); }
__device__ __forceinline__ void sincos_f32cr(float t, float& s, float& c) {
    double ds, dc;
    sincos((double)t, &ds, &dc);
    s = (float)ds; c = (float)dc;
}

__device__ __forceinline__ void legendre_cbf(float cs, const float* sphc,
                                             float* cbf) {
#pragma clang fp contract(off)
    float P0 = 1.0f, P1 = cs;
    cbf[0] = sphc[0];
    cbf[1] = sphc[1] * cs;
#pragma unroll
    for (int l = 1; l < L_SPH - 1; l++) {
        float a  = (float)(2 * l + 1) * cs;    // ((2l+1)*cos)*P_cur - l*P_prev
        float b  = a * P1;
        float d  = b - (float)l * P0;
        float Pn = d / (float)(l + 1);
        P0 = P1; P1 = Pn;
        cbf[l + 1] = sphc[l + 1] * Pn;
    }
}

// ---------------- kernel 0: materialize z/nrm LUT (static indices only) ------
// Dynamic indexing into a by-value struct would force a per-thread scratch
// copy (rule #20); instead ONE thread writes the 84-entry LUT with fully
// unrolled compile-time indices. tab[0..41]=z, tab[42..83]=nrm (flat j=l*6+n).

__global__ __launch_bounds__(64) void init_tab(float* __restrict__ tab, SBConsts c) {
    if (blockIdx.x != 0 || threadIdx.x != 0) return;
#pragma unroll
    for (int l = 0; l < L_SPH; l++)
#pragma unroll
        for (int n = 0; n < K_RAD; n++) {
            tab[l * K_RAD + n]      = c.z[l][n];
            tab[42 + l * K_RAD + n] = c.nrm[l][n];
        }
}

// ---------------- kernel 1: per-edge scalars (dist, x, env, dir) -------------

__global__ __launch_bounds__(TPB) void edge_pre(
        const float* __restrict__ d, float* __restrict__ rbf,
        float4* __restrict__ nd4, int nE) {
#pragma clang fp contract(off)
    int e = blockIdx.x * TPB + threadIdx.x;
    if (e >= nE) return;
    float dx = d[3 * e], dy = d[3 * e + 1], dz = d[3 * e + 2];
    float s = dx * dx;
    s = s + dy * dy;
    s = s + dz * dz;
    float dist = (float)sqrt((double)s);   // correctly-rounded f32 sqrt
    float nx = dx / dist, ny = dy / dist, nz = dz / dist;
    float x = dist / 5.0f;                 // CUTOFF = 5
    // envelope p=6: 1/x - 28 x^5 + 48 x^6 - 21 x^7 (order as reference)
    float x2 = x * x, x4 = x2 * x2;
    float x5 = x4 * x, x6 = x5 * x, x7 = x6 * x;
    float env = 1.0f / x;
    env = env + (-28.0f) * x5;
    env = env + 48.0f * x6;
    env = env + (-21.0f) * x7;
    nd4[e] = make_float4(nx, ny, nz, 0.0f);          // receiver-side gather table
    float* row = rbf + (size_t)e * RSTR;
    f32x2 xe; xe.x = x; xe.y = env;
    *(f32x2*)(row + 42) = xe;                        // byte 168, 8B-aligned
    f32x4 dir; dir.x = nx; dir.y = ny; dir.z = nz; dir.w = 0.0f;
    *(f32x4*)(row + 44) = dir;                       // byte 176, 16B-aligned
}

// ---------------- kernel 2: one thread per (edge, basis-element) -------------
// Bit-replicates the numpy float32 pipeline per element:
//   t = x*z32[j]; j0 = sin/t; j1 = sin/t^2 - cos/t;
//   j,jp = jp, ((2i+1)/t)*jp - j   (div, mul, sub — NO fma; runtime (float)(2i+1)
//   converts to the same f32 constants as the old unrolled version)
// Divergence: a wave spans l=0..6 (loop trip 0..5) — ~5 masked f32 iters, trivial
// next to the f64 sincos. Occupancy is the point: tiny per-thread state vs the
// old 184-VGPR row[42] monolith.

__global__ __launch_bounds__(TPB, 4) void edge_basis(
        const float* __restrict__ tab, float* __restrict__ rbf, int nE) {
#pragma clang fp contract(off)
    int i = blockIdx.x * TPB + threadIdx.x;
    if (i >= nE * LK) return;
    unsigned ui = (unsigned)i;
    unsigned e = ui / (unsigned)LK;                  // magic-mul
    int j = (int)(ui - e * (unsigned)LK);
    const float* row = rbf + (size_t)e * RSTR;
    f32x2 xe = *(const f32x2*)(row + 42);            // x, env (L1: 42 threads share)
    float x = xe.x, env = xe.y;
    float zj = tab[j], nrmj = tab[42 + j];           // L1-resident 336B LUT
    int l = j / K_RAD;
    float t = x * zj;
    float sn, co;
    if (l == 0) { sn = sin_f32cr(t); co = 0.0f; }    // cos unused at l=0
    else        { sincos_f32cr(t, sn, co); }
    float jj = sn / t;                               // j_0
    if (l > 0) {
        float t2 = t * t;
        float a1 = sn / t2;
        float a2 = co / t;
        float jp = a1 - a2;                          // j_1 (cancellation preserved)
        for (int ii = 1; ii < l; ii++) {
            float q  = (float)(2 * ii + 1) / t;
            float m  = q * jp;
            float nj = m - jj;
            jj = jp; jp = nj;
        }
        jj = jp;
    }
    float rb = nrmj * jj;
    rbf[(size_t)e * RSTR + j] = rb * env;
}

// ---------------- kernel 3: per-pair gather + Legendre + outer product -------
// 1 wave/block. LDS is an UNPADDED exact image of the block's output region:
//  - float2 LDS writes at dword-stride 42 are 2-way bank aliased (free),
//  - copy-out is a straight float4 memcpy (coalesced, full-line NT stores).

__global__ __launch_bounds__(PTPB, 4) void pair_kernel(
        const int* __restrict__ snd, const int* __restrict__ rcv,
        const float* __restrict__ rbf, const float4* __restrict__ nd4,
        float* __restrict__ out, int nP, SBConsts c) {
#pragma clang fp contract(off)
    __shared__ float so[PTPB * LK];                  // 10,752 B
    int p = blockIdx.x * PTPB + threadIdx.x;
    if (p < nP) {
        int s = snd[p], r = rcv[p];
        const float4* rowp = (const float4*)(rbf + (size_t)s * RSTR);
        float4 v[12];
#pragma unroll
        for (int q = 0; q < 12; q++) v[q] = rowp[q]; // 12x dwordx4, exactly 3 sectors
        float4 b = nd4[r];
        float ax = v[11].x, ay = v[11].y, az = v[11].z;   // sender dir (floats 44-46,
        float cs = ax * b.x;                              //  same bits as nd4[s])
        cs = cs + ay * b.y;                        // left-to-right like einsum
        cs = cs + az * b.z;
        float cbf[L_SPH];
        legendre_cbf(cs, c.sphc, cbf);
        float2* my = (float2*)&so[threadIdx.x * LK];      // 168B row, 8B aligned
#pragma unroll
        for (int q = 0; q < 10; q++) {
            float4 vq = v[q];
            my[2 * q]     = make_float2(vq.x * cbf[(4 * q + 0) / K_RAD],
                                        vq.y * cbf[(4 * q + 1) / K_RAD]);
            my[2 * q + 1] = make_float2(vq.z * cbf[(4 * q + 2) / K_RAD],
                                        vq.w * cbf[(4 * q + 3) / K_RAD]);
        }
        my[20] = make_float2(v[10].x * cbf[6], v[10].y * cbf[6]);  // j=40,41
    }
    __syncthreads();                                 // single wave: near-free
    size_t base  = (size_t)blockIdx.x * (PTPB * LK);
    size_t limit = (size_t)nP * LK;
    if (base + PTPB * LK <= limit) {
        f32x4* o4 = (f32x4*)(out + base);            // base = blk*10752B, 16B ok
        const f32x4* s4 = (const f32x4*)so;
#pragma unroll
        for (int k = 0; k < 10; k++)
            __builtin_nontemporal_store(s4[threadIdx.x + k * PTPB],
                                        &o4[threadIdx.x + k * PTPB]);
        f32x2* o2 = (f32x2*)(out + base + 2560);     // floats 2560..2687
        const f32x2* s2 = (const f32x2*)(so + 2560);
        __builtin_nontemporal_store(s2[threadIdx.x], &o2[threadIdx.x]);
    } else {
        for (int k = 0; k < LK; k++) {
            size_t g = base + threadIdx.x + (size_t)k * PTPB;
            if (g < limit) out[g] = so[threadIdx.x + k * PTPB];
        }
    }
}

// ---------------- fallback: fully fused per-pair (no workspace) --------------

__device__ void edge_row_f32(float dx, float dy, float dz, const SBConsts& c,
                             float* row, float& nx, float& ny, float& nz) {
#pragma clang fp contract(off)
    float s = dx * dx;
    s = s + dy * dy;
    s = s + dz * dz;
    float dist = (float)sqrt((double)s);
    nx = dx / dist; ny = dy / dist; nz = dz / dist;
    float x = dist / 5.0f;
    float x2 = x * x, x4 = x2 * x2;
    float x5 = x4 * x, x6 = x5 * x, x7 = x6 * x;
    float env = 1.0f / x;
    env = env + (-28.0f) * x5;
    env = env + 48.0f * x6;
    env = env + (-21.0f) * x7;
#pragma unroll
    for (int l = 0; l < L_SPH; l++) {
#pragma unroll
        for (int n = 0; n < K_RAD; n++) {
            float t  = x * c.z[l][n];
            float sn, co;
            if (l == 0) { sn = sin_f32cr(t); co = 0.0f; }
            else        { sincos_f32cr(t, sn, co); }
            float j  = sn / t;
            if (l > 0) {
                float t2 = t * t;
                float a1 = sn / t2;
                float a2 = co / t;
                float jp = a1 - a2;
#pragma unroll
                for (int i = 1; i < l; i++) {
                    float q  = (float)(2 * i + 1) / t;
                    float m  = q * jp;
                    float nj = m - j;
                    j = jp; jp = nj;
                }
                j = jp;
            }
            float rb = c.nrm[l][n] * j;
            row[l * K_RAD + n] = rb * env;
        }
    }
}

__global__ __launch_bounds__(TPB) void fused_kernel(
        const float* __restrict__ d, const int* __restrict__ snd,
        const int* __restrict__ rcv, float* __restrict__ out,
        int nP, SBConsts c) {
#pragma clang fp contract(off)
    int p = blockIdx.x * TPB + threadIdx.x;
    if (p >= nP) return;
    int s = snd[p], r = rcv[p];
    float row[LK], sx, sy, sz;
    edge_row_f32(d[3 * s], d[3 * s + 1], d[3 * s + 2], c, row, sx, sy, sz);
    float rx = d[3 * r], ry = d[3 * r + 1], rz = d[3 * r + 2];
    float t = rx * rx;  t = t + ry * ry;  t = t + rz * rz;
    float rd = (float)sqrt((double)t);
    float cs = sx * (rx / rd);
    cs = cs + sy * (ry / rd);
    cs = cs + sz * (rz / rd);
    float cbf[L_SPH];
    legendre_cbf(cs, c.sphc, cbf);
    float* o = out + (size_t)p * LK;
#pragma unroll
    for (int j = 0; j < LK; j++) o[j] = row[j] * cbf[j / K_RAD];
}

// ---------------- launch -----------------------------------------------------

extern "C" void kernel_launch(void* const* d_in, const int* in_sizes, int n_in,
                              void* d_out, int out_size, void* d_ws, size_t ws_size,
                              hipStream_t stream) {
    static SBConsts c = make_consts();
    const float* dists = (const float*)d_in[0];
    const int*   snd   = (const int*)d_in[1];
    const int*   rcv   = (const int*)d_in[2];
    float*       out   = (float*)d_out;
    int nE = in_sizes[0] / 3;
    int nP = in_sizes[1];

    size_t rbf_b = (size_t)nE * RSTR * sizeof(float);   // 96 MB, 192B rows
    size_t nd4_b = (size_t)nE * sizeof(float4);         //  8 MB
    size_t tab_b = 512;                                 // 84-float LUT (aligned)
    size_t need  = rbf_b + nd4_b + tab_b;

    if (ws_size >= need) {
        float*  rbf = (float*)d_ws;
        float4* nd4 = (float4*)((char*)d_ws + rbf_b);
        float*  tab = (float*)((char*)d_ws + rbf_b + nd4_b);
        int nB = nE * LK;                               // 21M basis elements
        init_tab  <<<1, 64, 0, stream>>>(tab, c);
        edge_pre  <<<(nE + TPB - 1) / TPB, TPB, 0, stream>>>(dists, rbf, nd4, nE);
        edge_basis<<<(nB + TPB - 1) / TPB, TPB, 0, stream>>>(tab, rbf, nE);
        pair_kernel<<<(nP + PTPB - 1) / PTPB, PTPB, 0, stream>>>(snd, rcv, rbf, nd4, out, nP, c);
    } else {
        fused_kernel<<<(nP + TPB - 1) / TPB, TPB, 0, stream>>>(dists, snd, rcv, out, nP, c);
    }
}

// Round 7
// 537.851 us; speedup vs baseline: 1.0988x; 1.0988x over previous
//
#include <hip/hip_runtime.h>
#include <math.h>

#define L_SPH 7
#define K_RAD 6
#define LK    42          // L*K
#define TPB   256
#define PTPB  64          // pair-kernel block: 1 wave -> 10.75KB LDS
#define RSTR  48          // rbf row stride (floats): 192B = 3x64B sectors.
                          // [0..41]=basis, [42]=x, [43]=env, [44..46]=dir, [47]=0
#define EPB   64          // edges per edge_fused block
#define LSTR  49          // LDS row stride (odd -> column writes spread all 32 banks)

// ROUND-6 POST-MORTEM: splitting edge into per-element threads bought ~0
// (591us vs 586): waves spanned all l -> divergent dual trig call (sin AND
// sincos serially) + masked recurrences; per-element gathers stayed. This
// round: fused edge kernel, 64 edges/block, each WAVE owns one j-column ->
// l, z, nrm wave-uniform (scalar branch, single trig path), 64 independent
// sincos lanes, LDS stride-49 transpose, coalesced f32x4 NT row writes.
// Bit-identical arithmetic per element.
// ROUND-4 (sort-by-sender, REVERTED): reordered writes are transaction-bound;
// pair stays in round-3 form (sector-minimal gathers + LDS full-line writes).

typedef float f32x4 __attribute__((ext_vector_type(4)));
typedef float f32x2 __attribute__((ext_vector_type(2)));

// ---------------- host-side constants (replicates numpy bisection exactly) ---

struct SBConsts {
    float z[L_SPH][K_RAD];     // Bessel zeros z_{l,n}, rounded to f32 like ref
    float nrm[L_SPH][K_RAD];   // normalizers c_{l,n}, rounded to f32 like ref
    float sphc[L_SPH];         // sqrt((2l+1)/4pi), f32
};

static double host_sph_jn(double r, int l) {
    double j = sin(r) / r;
    if (l == 0) return j;
    double jp = sin(r) / (r * r) - cos(r) / r;
    for (int i = 1; i < l; i++) {
        double t = (2.0 * i + 1.0) / r * jp - j;
        j = jp; jp = t;
    }
    return jp;
}

static SBConsts make_consts() {
    const int L = L_SPH, K = K_RAD;
    double prev[L + K];
    for (int i = 0; i < L + K; i++) prev[i] = (i + 1) * M_PI;
    int plen = L + K;
    double zeros[L_SPH][K_RAD];
    for (int n = 0; n < K; n++) zeros[0][n] = prev[n];
    for (int l = 1; l < L; l++) {
        int m = plen - 1;
        double lo[L + K], hi[L + K], flo[L + K];
        for (int i = 0; i < m; i++) {
            lo[i] = prev[i]; hi[i] = prev[i + 1];
            flo[i] = host_sph_jn(lo[i], l);
        }
        for (int it = 0; it < 100; it++) {
            for (int i = 0; i < m; i++) {
                double mid = 0.5 * (lo[i] + hi[i]);
                double fm  = host_sph_jn(mid, l);
                bool same  = (fm >= 0.0) == (flo[i] >= 0.0);
                if (same) { lo[i] = mid; flo[i] = fm; }
                else      { hi[i] = mid; }
            }
        }
        for (int i = 0; i < m; i++) prev[i] = 0.5 * (lo[i] + hi[i]);
        plen = m;
        for (int n = 0; n < K; n++) zeros[l][n] = prev[n];
    }
    SBConsts c;
    for (int l = 0; l < L; l++) {
        for (int n = 0; n < K; n++) {
            c.z[l][n] = (float)zeros[l][n];
            double j1 = host_sph_jn(zeros[l][n], l + 1);
            c.nrm[l][n] = (float)(1.0 / sqrt(0.5 * j1 * j1));
        }
        c.sphc[l] = (float)sqrt((2.0 * l + 1.0) / (4.0 * M_PI));
    }
    return c;
}

// ---------------- device helpers --------------------------------------------
// f64-evaluate, round once to f32 (proxy for numpy f32 trig; see prior rounds).
__device__ __forceinline__ float sin_f32cr(float t) { return (float)sin((double)t); }
__device__ __forceinline__ void sincos_f32cr(float t, float& s, float& c) {
    double ds, dc;
    sincos((double)t, &ds, &dc);
    s = (float)ds; c = (float)dc;
}

__device__ __forceinline__ void legendre_cbf(float cs, const float* sphc,
                                             float* cbf) {
#pragma clang fp contract(off)
    float P0 = 1.0f, P1 = cs;
    cbf[0] = sphc[0];
    cbf[1] = sphc[1] * cs;
#pragma unroll
    for (int l = 1; l < L_SPH - 1; l++) {
        float a  = (float)(2 * l + 1) * cs;    // ((2l+1)*cos)*P_cur - l*P_prev
        float b  = a * P1;
        float d  = b - (float)l * P0;
        float Pn = d / (float)(l + 1);
        P0 = P1; P1 = Pn;
        cbf[l + 1] = sphc[l + 1] * Pn;
    }
}

// ---------------- kernel 0: materialize z/nrm LUT (static indices only) ------
// (dynamic indexing into a by-value struct would scratch-spill — rule #20)

__global__ __launch_bounds__(64) void init_tab(float* __restrict__ tab, SBConsts c) {
    if (blockIdx.x != 0 || threadIdx.x != 0) return;
#pragma unroll
    for (int l = 0; l < L_SPH; l++)
#pragma unroll
        for (int n = 0; n < K_RAD; n++) {
            tab[l * K_RAD + n]      = c.z[l][n];
            tab[42 + l * K_RAD + n] = c.nrm[l][n];
        }
}

// ---------------- kernel 1: fused per-edge basis (wave-uniform j) ------------
// Block = 256 threads <-> 64 edges.
//  phase 1: wave 0 computes dist/x/env/dir per edge (coalesced), -> LDS + nd4
//  phase 2: (wave, chunk) owns ONE j-column: l/z/nrm uniform -> scalar branch,
//           single trig path (l=0 waves run sin only, bit-preserving), lanes =
//           64 independent edges. LDS stride 49: column store hits all 32 banks.
//  phase 3: identity copy-out to 192B rows, coalesced f32x4 NT stores.

__global__ __launch_bounds__(TPB, 4) void edge_fused(
        const float* __restrict__ d, const float* __restrict__ tab,
        float* __restrict__ rbf, float4* __restrict__ nd4, int nE) {
#pragma clang fp contract(off)
    __shared__ float lds[EPB * LSTR];              // 12,544 B
    __shared__ float xe[EPB * 2];                  // x, env per edge
    int t  = threadIdx.x;
    int e0 = blockIdx.x * EPB;
    int rows = nE - e0; if (rows > EPB) rows = EPB;

    if (t < EPB && t < rows) {                     // ---- phase 1 (wave 0)
        int e = e0 + t;
        float dx = d[3 * e], dy = d[3 * e + 1], dz = d[3 * e + 2];
        float s = dx * dx;
        s = s + dy * dy;
        s = s + dz * dz;
        float dist = (float)sqrt((double)s);       // correctly-rounded f32 sqrt
        float nx = dx / dist, ny = dy / dist, nz = dz / dist;
        float x = dist / 5.0f;                     // CUTOFF = 5
        float x2 = x * x, x4 = x2 * x2;
        float x5 = x4 * x, x6 = x5 * x, x7 = x6 * x;
        float env = 1.0f / x;
        env = env + (-28.0f) * x5;
        env = env + 48.0f * x6;
        env = env + (-21.0f) * x7;
        nd4[e] = make_float4(nx, ny, nz, 0.0f);    // receiver-side gather table
        xe[2 * t] = x; xe[2 * t + 1] = env;
        float* lrow = &lds[t * LSTR];
        lrow[42] = x;  lrow[43] = env;
        lrow[44] = nx; lrow[45] = ny; lrow[46] = nz; lrow[47] = 0.0f;
    }
    __syncthreads();

    int lane = t & 63, wid = t >> 6;               // ---- phase 2
    float x = xe[2 * lane], env = xe[2 * lane + 1];
#pragma unroll 1
    for (int cc = 0; cc < 11; cc++) {
        int j = cc * 4 + wid;                      // wave-uniform column index
        if (j < LK && lane < rows) {
            float zj = tab[j], nrmj = tab[42 + j]; // uniform -> broadcast load
            int l = j / K_RAD;                     // uniform -> scalar branch
            float tt = x * zj;
            float sn, co;
            if (l == 0) { sn = sin_f32cr(tt); }    // whole wave takes ONE path
            else        { sincos_f32cr(tt, sn, co); }
            float jj = sn / tt;                    // j_0
            if (l > 0) {
                float t2 = tt * tt;
                float a1 = sn / t2;
                float a2 = co / tt;
                float jp = a1 - a2;                // j_1 (cancellation preserved)
                for (int ii = 1; ii < l; ii++) {   // uniform trip count
                    float q  = (float)(2 * ii + 1) / tt;
                    float m  = q * jp;
                    float nj = m - jj;
                    jj = jp; jp = nj;
                }
                jj = jp;
            }
            float rb = nrmj * jj;
            lds[lane * LSTR + j] = rb * env;       // stride-49: conflict-free
        }
    }
    __syncthreads();

    float* obase = rbf + (size_t)e0 * RSTR;        // ---- phase 3 (identity copy)
    int nvec = rows * (RSTR / 4);                  // rows*12 f32x4
#pragma unroll
    for (int k = 0; k < 3; k++) {
        int idx4 = t + k * TPB;
        if (idx4 < nvec) {
            int r  = idx4 / 12;
            int c4 = idx4 - r * 12;
            const float* lp = &lds[r * LSTR + c4 * 4];
            f32x4 v; v.x = lp[0]; v.y = lp[1]; v.z = lp[2]; v.w = lp[3];
            __builtin_nontemporal_store(v, (f32x4*)obase + idx4);
        }
    }
}

// ---------------- kernel 2: per-pair gather + Legendre + outer product -------
// 1 wave/block. LDS is an UNPADDED exact image of the block's output region.

__global__ __launch_bounds__(PTPB, 4) void pair_kernel(
        const int* __restrict__ snd, const int* __restrict__ rcv,
        const float* __restrict__ rbf, const float4* __restrict__ nd4,
        float* __restrict__ out, int nP, SBConsts c) {
#pragma clang fp contract(off)
    __shared__ float so[PTPB * LK];                  // 10,752 B
    int p = blockIdx.x * PTPB + threadIdx.x;
    if (p < nP) {
        int s = snd[p], r = rcv[p];
        const float4* rowp = (const float4*)(rbf + (size_t)s * RSTR);
        float4 v[12];
#pragma unroll
        for (int q = 0; q < 12; q++) v[q] = rowp[q]; // 12x dwordx4, exactly 3 sectors
        float4 b = nd4[r];
        float ax = v[11].x, ay = v[11].y, az = v[11].z;   // sender dir (floats 44-46)
        float cs = ax * b.x;
        cs = cs + ay * b.y;                        // left-to-right like einsum
        cs = cs + az * b.z;
        float cbf[L_SPH];
        legendre_cbf(cs, c.sphc, cbf);
        float2* my = (float2*)&so[threadIdx.x * LK];      // 168B row, 8B aligned
#pragma unroll
        for (int q = 0; q < 10; q++) {
            float4 vq = v[q];
            my[2 * q]     = make_float2(vq.x * cbf[(4 * q + 0) / K_RAD],
                                        vq.y * cbf[(4 * q + 1) / K_RAD]);
            my[2 * q + 1] = make_float2(vq.z * cbf[(4 * q + 2) / K_RAD],
                                        vq.w * cbf[(4 * q + 3) / K_RAD]);
        }
        my[20] = make_float2(v[10].x * cbf[6], v[10].y * cbf[6]);  // j=40,41
    }
    __syncthreads();                                 // single wave: near-free
    size_t base  = (size_t)blockIdx.x * (PTPB * LK);
    size_t limit = (size_t)nP * LK;
    if (base + PTPB * LK <= limit) {
        f32x4* o4 = (f32x4*)(out + base);            // base = blk*10752B, 16B ok
        const f32x4* s4 = (const f32x4*)so;
#pragma unroll
        for (int k = 0; k < 10; k++)
            __builtin_nontemporal_store(s4[threadIdx.x + k * PTPB],
                                        &o4[threadIdx.x + k * PTPB]);
        f32x2* o2 = (f32x2*)(out + base + 2560);     // floats 2560..2687
        const f32x2* s2 = (const f32x2*)(so + 2560);
        __builtin_nontemporal_store(s2[threadIdx.x], &o2[threadIdx.x]);
    } else {
        for (int k = 0; k < LK; k++) {
            size_t g = base + threadIdx.x + (size_t)k * PTPB;
            if (g < limit) out[g] = so[threadIdx.x + k * PTPB];
        }
    }
}

// ---------------- fallback: fully fused per-pair (no workspace) --------------

__device__ void edge_row_f32(float dx, float dy, float dz, const SBConsts& c,
                             float* row, float& nx, float& ny, float& nz) {
#pragma clang fp contract(off)
    float s = dx * dx;
    s = s + dy * dy;
    s = s + dz * dz;
    float dist = (float)sqrt((double)s);
    nx = dx / dist; ny = dy / dist; nz = dz / dist;
    float x = dist / 5.0f;
    float x2 = x * x, x4 = x2 * x2;
    float x5 = x4 * x, x6 = x5 * x, x7 = x6 * x;
    float env = 1.0f / x;
    env = env + (-28.0f) * x5;
    env = env + 48.0f * x6;
    env = env + (-21.0f) * x7;
#pragma unroll
    for (int l = 0; l < L_SPH; l++) {
#pragma unroll
        for (int n = 0; n < K_RAD; n++) {
            float t  = x * c.z[l][n];
            float sn, co;
            if (l == 0) { sn = sin_f32cr(t); co = 0.0f; }
            else        { sincos_f32cr(t, sn, co); }
            float j  = sn / t;
            if (l > 0) {
                float t2 = t * t;
                float a1 = sn / t2;
                float a2 = co / t;
                float jp = a1 - a2;
#pragma unroll
                for (int i = 1; i < l; i++) {
                    float q  = (float)(2 * i + 1) / t;
                    float m  = q * jp;
                    float nj = m - j;
                    j = jp; jp = nj;
                }
                j = jp;
            }
            float rb = c.nrm[l][n] * j;
            row[l * K_RAD + n] = rb * env;
        }
    }
}

__global__ __launch_bounds__(TPB) void fused_kernel(
        const float* __restrict__ d, const int* __restrict__ snd,
        const int* __restrict__ rcv, float* __restrict__ out,
        int nP, SBConsts c) {
#pragma clang fp contract(off)
    int p = blockIdx.x * TPB + threadIdx.x;
    if (p >= nP) return;
    int s = snd[p], r = rcv[p];
    float row[LK], sx, sy, sz;
    edge_row_f32(d[3 * s], d[3 * s + 1], d[3 * s + 2], c, row, sx, sy, sz);
    float rx = d[3 * r], ry = d[3 * r + 1], rz = d[3 * r + 2];
    float t = rx * rx;  t = t + ry * ry;  t = t + rz * rz;
    float rd = (float)sqrt((double)t);
    float cs = sx * (rx / rd);
    cs = cs + sy * (ry / rd);
    cs = cs + sz * (rz / rd);
    float cbf[L_SPH];
    legendre_cbf(cs, c.sphc, cbf);
    float* o = out + (size_t)p * LK;
#pragma unroll
    for (int j = 0; j < LK; j++) o[j] = row[j] * cbf[j / K_RAD];
}

// ---------------- launch -----------------------------------------------------

extern "C" void kernel_launch(void* const* d_in, const int* in_sizes, int n_in,
                              void* d_out, int out_size, void* d_ws, size_t ws_size,
                              hipStream_t stream) {
    static SBConsts c = make_consts();
    const float* dists = (const float*)d_in[0];
    const int*   snd   = (const int*)d_in[1];
    const int*   rcv   = (const int*)d_in[2];
    float*       out   = (float*)d_out;
    int nE = in_sizes[0] / 3;
    int nP = in_sizes[1];

    size_t rbf_b = (size_t)nE * RSTR * sizeof(float);   // 96 MB, 192B rows
    size_t nd4_b = (size_t)nE * sizeof(float4);         //  8 MB
    size_t tab_b = 512;                                 // 84-float LUT
    size_t need  = rbf_b + nd4_b + tab_b;

    if (ws_size >= need) {
        float*  rbf = (float*)d_ws;
        float4* nd4 = (float4*)((char*)d_ws + rbf_b);
        float*  tab = (float*)((char*)d_ws + rbf_b + nd4_b);
        init_tab  <<<1, 64, 0, stream>>>(tab, c);
        edge_fused<<<(nE + EPB - 1) / EPB, TPB, 0, stream>>>(dists, tab, rbf, nd4, nE);
        pair_kernel<<<(nP + PTPB - 1) / PTPB, PTPB, 0, stream>>>(snd, rcv, rbf, nd4, out, nP, c);
    } else {
        fused_kernel<<<(nP + TPB - 1) / TPB, TPB, 0, stream>>>(dists, snd, rcv, out, nP, c);
    }
}

// Round 9
// 532.784 us; speedup vs baseline: 1.1092x; 1.0095x over previous
//
#include <hip/hip_runtime.h>
#include <math.h>

#define L_SPH 7
#define K_RAD 6
#define LK    42          // L*K
#define TPB   256
#define PTPB  64          // pair-kernel block: 1 wave -> 10.75KB LDS
#define RSTR  48          // rbf row stride (floats): 192B = 3x64B sectors.
                          // [0..41]=basis, [42]=x, [43]=env, [44..46]=dir, [47]=0
#define EPB   64          // edges per edge_fused block
#define LSTR  49          // LDS row stride (odd -> column writes spread all 32 banks)

// ROUND-8: resubmit of round-7 kernel — bench died with GPUAcquisitionTimeout
// (broker capacity, no compile/run signal). No changes.
// ROUND-7 POST-MORTEM: wave-uniform j cut edge 240->188us (divergence was
// real). Decomposition: 537 = fill(212, harness-fixed) + edge(188) + pair(134).
// Edge is at the VALU floor for its op mix: 21M ocml f64 sincos (~60 ops ea,
// general-range) + 102M mandatory IEEE f32 divs. pair is at BW floor
// (870MB @ 6.3TB/s). THIS KERNEL: custom branch-free f64 sincos for |t|<100
// (2-term Cody-Waite + fdlibm deg-13/14 kernels, ~30 ops, no tables): ~0.6ulp
// f64 -> same-f32-rounding as ocml for all but ~0.04 EXPECTED elements of 21M.
// Everything else bit-identical.
// ROUND-4 (sort-by-sender, REVERTED): reordered writes are transaction-bound.

typedef float f32x4 __attribute__((ext_vector_type(4)));
typedef float f32x2 __attribute__((ext_vector_type(2)));

// ---------------- host-side constants (replicates numpy bisection exactly) ---

struct SBConsts {
    float z[L_SPH][K_RAD];     // Bessel zeros z_{l,n}, rounded to f32 like ref
    float nrm[L_SPH][K_RAD];   // normalizers c_{l,n}, rounded to f32 like ref
    float sphc[L_SPH];         // sqrt((2l+1)/4pi), f32
};

static double host_sph_jn(double r, int l) {
    double j = sin(r) / r;
    if (l == 0) return j;
    double jp = sin(r) / (r * r) - cos(r) / r;
    for (int i = 1; i < l; i++) {
        double t = (2.0 * i + 1.0) / r * jp - j;
        j = jp; jp = t;
    }
    return jp;
}

static SBConsts make_consts() {
    const int L = L_SPH, K = K_RAD;
    double prev[L + K];
    for (int i = 0; i < L + K; i++) prev[i] = (i + 1) * M_PI;
    int plen = L + K;
    double zeros[L_SPH][K_RAD];
    for (int n = 0; n < K; n++) zeros[0][n] = prev[n];
    for (int l = 1; l < L; l++) {
        int m = plen - 1;
        double lo[L + K], hi[L + K], flo[L + K];
        for (int i = 0; i < m; i++) {
            lo[i] = prev[i]; hi[i] = prev[i + 1];
            flo[i] = host_sph_jn(lo[i], l);
        }
        for (int it = 0; it < 100; it++) {
            for (int i = 0; i < m; i++) {
                double mid = 0.5 * (lo[i] + hi[i]);
                double fm  = host_sph_jn(mid, l);
                bool same  = (fm >= 0.0) == (flo[i] >= 0.0);
                if (same) { lo[i] = mid; flo[i] = fm; }
                else      { hi[i] = mid; }
            }
        }
        for (int i = 0; i < m; i++) prev[i] = 0.5 * (lo[i] + hi[i]);
        plen = m;
        for (int n = 0; n < K; n++) zeros[l][n] = prev[n];
    }
    SBConsts c;
    for (int l = 0; l < L; l++) {
        for (int n = 0; n < K; n++) {
            c.z[l][n] = (float)zeros[l][n];
            double j1 = host_sph_jn(zeros[l][n], l + 1);
            c.nrm[l][n] = (float)(1.0 / sqrt(0.5 * j1 * j1));
        }
        c.sphc[l] = (float)sqrt((2.0 * l + 1.0) / (4.0 * M_PI));
    }
    return c;
}

// ---------------- device helpers --------------------------------------------
// Fallback-path trig (ocml), f64-evaluate round-once-to-f32.
__device__ __forceinline__ float sin_f32cr(float t) { return (float)sin((double)t); }
__device__ __forceinline__ void sincos_f32cr(float t, float& s, float& c) {
    double ds, dc;
    sincos((double)t, &ds, &dc);
    s = (float)ds; c = (float)dc;
}

// Custom branch-free f64 sincos, valid |t| < ~1e6 (ours: t = x*z < ~100).
// 2-term Cody-Waite reduction (fn <= ~64 here; residual rounding ~1e-16 abs)
// + fdlibm __kernel_sin/__kernel_cos (deg 13/14). ~0.6 ulp f64 -> rounds to
// the same f32 as correctly-rounded for all but ~2e-9 of arguments.
__device__ __forceinline__ void sincos_cw_f32(float tf, float& sf, float& cf) {
    const double INV_PIO2 = 6.36619772367581382433e-01;
    const double PIO2_1   = 1.57079632673412561417e+00;   // 33-bit head
    const double PIO2_1T  = 6.07710050650619224932e-11;   // tail
    const double S1 = -1.66666666666666324348e-01, S2 = 8.33333333332248946124e-03,
                 S3 = -1.98412698298579493134e-04, S4 = 2.75573137070700676789e-06,
                 S5 = -2.50507602534068634195e-08, S6 = 1.58969099521155010221e-10;
    const double C1 =  4.16666666666666019037e-02, C2 = -1.38888888888741095749e-03,
                 C3 =  2.48015872894767294178e-05, C4 = -2.75573143513906633035e-07,
                 C5 =  2.08757232129817482790e-09, C6 = -1.13596475577881948265e-11;
    double td = (double)tf;
    double fn = rint(td * INV_PIO2);
    double r  = __builtin_fma(-fn, PIO2_1, td);
    r = __builtin_fma(-fn, PIO2_1T, r);
    int n = (int)fn & 3;
    double z = r * r;
    // sin kernel: r + r*z*(S1 + z*(...))
    double ps = __builtin_fma(z, S6, S5);
    ps = __builtin_fma(z, ps, S4);
    ps = __builtin_fma(z, ps, S3);
    ps = __builtin_fma(z, ps, S2);
    ps = __builtin_fma(z, ps, S1);
    double ss = __builtin_fma(r * z, ps, r);
    // cos kernel: fdlibm w-trick for the 1 - z/2 head
    double pc = __builtin_fma(z, C6, C5);
    pc = __builtin_fma(z, pc, C4);
    pc = __builtin_fma(z, pc, C3);
    pc = __builtin_fma(z, pc, C2);
    pc = __builtin_fma(z, pc, C1);
    double zr = z * pc;                       // z*(C1 + z*(...))
    double hz = 0.5 * z;
    double w  = 1.0 - hz;
    double cc = w + (((1.0 - w) - hz) + z * zr);
    // quadrant: n=0:(s,c)=(ss,cc) 1:(cc,-ss) 2:(-ss,-cc) 3:(-cc,ss)
    bool swap = (n & 1) != 0;
    double a = swap ? cc : ss;
    double b = swap ? ss : cc;
    double s = (n & 2) ? -a : a;
    double c = ((n + 1) & 2) ? -b : b;
    sf = (float)s; cf = (float)c;
}

__device__ __forceinline__ void legendre_cbf(float cs, const float* sphc,
                                             float* cbf) {
#pragma clang fp contract(off)
    float P0 = 1.0f, P1 = cs;
    cbf[0] = sphc[0];
    cbf[1] = sphc[1] * cs;
#pragma unroll
    for (int l = 1; l < L_SPH - 1; l++) {
        float a  = (float)(2 * l + 1) * cs;    // ((2l+1)*cos)*P_cur - l*P_prev
        float b  = a * P1;
        float d  = b - (float)l * P0;
        float Pn = d / (float)(l + 1);
        P0 = P1; P1 = Pn;
        cbf[l + 1] = sphc[l + 1] * Pn;
    }
}

// ---------------- kernel 0: materialize z/nrm LUT (static indices only) ------
// (dynamic indexing into a by-value struct would scratch-spill — rule #20)

__global__ __launch_bounds__(64) void init_tab(float* __restrict__ tab, SBConsts c) {
    if (blockIdx.x != 0 || threadIdx.x != 0) return;
#pragma unroll
    for (int l = 0; l < L_SPH; l++)
#pragma unroll
        for (int n = 0; n < K_RAD; n++) {
            tab[l * K_RAD + n]      = c.z[l][n];
            tab[42 + l * K_RAD + n] = c.nrm[l][n];
        }
}

// ---------------- kernel 1: fused per-edge basis (wave-uniform j) ------------
// Block = 256 threads <-> 64 edges.
//  phase 1: wave 0 computes dist/x/env/dir per edge (coalesced), -> LDS + nd4
//  phase 2: (wave, chunk) owns ONE j-column: l/z/nrm uniform -> scalar branch,
//           single trig path, lanes = 64 independent edges, custom sincos.
//  phase 3: identity copy-out to 192B rows, coalesced f32x4 NT stores.

__global__ __launch_bounds__(TPB, 4) void edge_fused(
        const float* __restrict__ d, const float* __restrict__ tab,
        float* __restrict__ rbf, float4* __restrict__ nd4, int nE) {
#pragma clang fp contract(off)
    __shared__ float lds[EPB * LSTR];              // 12,544 B
    __shared__ float xe[EPB * 2];                  // x, env per edge
    int t  = threadIdx.x;
    int e0 = blockIdx.x * EPB;
    int rows = nE - e0; if (rows > EPB) rows = EPB;

    if (t < EPB && t < rows) {                     // ---- phase 1 (wave 0)
        int e = e0 + t;
        float dx = d[3 * e], dy = d[3 * e + 1], dz = d[3 * e + 2];
        float s = dx * dx;
        s = s + dy * dy;
        s = s + dz * dz;
        float dist = (float)sqrt((double)s);       // correctly-rounded f32 sqrt
        float nx = dx / dist, ny = dy / dist, nz = dz / dist;
        float x = dist / 5.0f;                     // CUTOFF = 5
        float x2 = x * x, x4 = x2 * x2;
        float x5 = x4 * x, x6 = x5 * x, x7 = x6 * x;
        float env = 1.0f / x;
        env = env + (-28.0f) * x5;
        env = env + 48.0f * x6;
        env = env + (-21.0f) * x7;
        nd4[e] = make_float4(nx, ny, nz, 0.0f);    // receiver-side gather table
        xe[2 * t] = x; xe[2 * t + 1] = env;
        float* lrow = &lds[t * LSTR];
        lrow[42] = x;  lrow[43] = env;
        lrow[44] = nx; lrow[45] = ny; lrow[46] = nz; lrow[47] = 0.0f;
    }
    __syncthreads();

    int lane = t & 63, wid = t >> 6;               // ---- phase 2
    float x = xe[2 * lane], env = xe[2 * lane + 1];
#pragma unroll 1
    for (int cc = 0; cc < 11; cc++) {
        int j = cc * 4 + wid;                      // wave-uniform column index
        if (j < LK && lane < rows) {
            float zj = tab[j], nrmj = tab[42 + j]; // uniform -> broadcast load
            int l = j / K_RAD;                     // uniform -> scalar branch
            float tt = x * zj;
            float sn, co;
            sincos_cw_f32(tt, sn, co);             // custom small-arg f64 sincos
            float jj = sn / tt;                    // j_0
            if (l > 0) {
                float t2 = tt * tt;
                float a1 = sn / t2;
                float a2 = co / tt;
                float jp = a1 - a2;                // j_1 (cancellation preserved)
                for (int ii = 1; ii < l; ii++) {   // uniform trip count
                    float q  = (float)(2 * ii + 1) / tt;
                    float m  = q * jp;
                    float nj = m - jj;
                    jj = jp; jp = nj;
                }
                jj = jp;
            }
            float rb = nrmj * jj;
            lds[lane * LSTR + j] = rb * env;       // stride-49: conflict-free
        }
    }
    __syncthreads();

    float* obase = rbf + (size_t)e0 * RSTR;        // ---- phase 3 (identity copy)
    int nvec = rows * (RSTR / 4);                  // rows*12 f32x4
#pragma unroll
    for (int k = 0; k < 3; k++) {
        int idx4 = t + k * TPB;
        if (idx4 < nvec) {
            int r  = idx4 / 12;
            int c4 = idx4 - r * 12;
            const float* lp = &lds[r * LSTR + c4 * 4];
            f32x4 v; v.x = lp[0]; v.y = lp[1]; v.z = lp[2]; v.w = lp[3];
            __builtin_nontemporal_store(v, (f32x4*)obase + idx4);
        }
    }
}

// ---------------- kernel 2: per-pair gather + Legendre + outer product -------
// 1 wave/block. LDS is an UNPADDED exact image of the block's output region.

__global__ __launch_bounds__(PTPB, 4) void pair_kernel(
        const int* __restrict__ snd, const int* __restrict__ rcv,
        const float* __restrict__ rbf, const float4* __restrict__ nd4,
        float* __restrict__ out, int nP, SBConsts c) {
#pragma clang fp contract(off)
    __shared__ float so[PTPB * LK];                  // 10,752 B
    int p = blockIdx.x * PTPB + threadIdx.x;
    if (p < nP) {
        int s = snd[p], r = rcv[p];
        const float4* rowp = (const float4*)(rbf + (size_t)s * RSTR);
        float4 v[12];
#pragma unroll
        for (int q = 0; q < 12; q++) v[q] = rowp[q]; // 12x dwordx4, exactly 3 sectors
        float4 b = nd4[r];
        float ax = v[11].x, ay = v[11].y, az = v[11].z;   // sender dir (floats 44-46)
        float cs = ax * b.x;
        cs = cs + ay * b.y;                        // left-to-right like einsum
        cs = cs + az * b.z;
        float cbf[L_SPH];
        legendre_cbf(cs, c.sphc, cbf);
        float2* my = (float2*)&so[threadIdx.x * LK];      // 168B row, 8B aligned
#pragma unroll
        for (int q = 0; q < 10; q++) {
            float4 vq = v[q];
            my[2 * q]     = make_float2(vq.x * cbf[(4 * q + 0) / K_RAD],
                                        vq.y * cbf[(4 * q + 1) / K_RAD]);
            my[2 * q + 1] = make_float2(vq.z * cbf[(4 * q + 2) / K_RAD],
                                        vq.w * cbf[(4 * q + 3) / K_RAD]);
        }
        my[20] = make_float2(v[10].x * cbf[6], v[10].y * cbf[6]);  // j=40,41
    }
    __syncthreads();                                 // single wave: near-free
    size_t base  = (size_t)blockIdx.x * (PTPB * LK);
    size_t limit = (size_t)nP * LK;
    if (base + PTPB * LK <= limit) {
        f32x4* o4 = (f32x4*)(out + base);            // base = blk*10752B, 16B ok
        const f32x4* s4 = (const f32x4*)so;
#pragma unroll
        for (int k = 0; k < 10; k++)
            __builtin_nontemporal_store(s4[threadIdx.x + k * PTPB],
                                        &o4[threadIdx.x + k * PTPB]);
        f32x2* o2 = (f32x2*)(out + base + 2560);     // floats 2560..2687
        const f32x2* s2 = (const f32x2*)(so + 2560);
        __builtin_nontemporal_store(s2[threadIdx.x], &o2[threadIdx.x]);
    } else {
        for (int k = 0; k < LK; k++) {
            size_t g = base + threadIdx.x + (size_t)k * PTPB;
            if (g < limit) out[g] = so[threadIdx.x + k * PTPB];
        }
    }
}

// ---------------- fallback: fully fused per-pair (no workspace) --------------

__device__ void edge_row_f32(float dx, float dy, float dz, const SBConsts& c,
                             float* row, float& nx, float& ny, float& nz) {
#pragma clang fp contract(off)
    float s = dx * dx;
    s = s + dy * dy;
    s = s + dz * dz;
    float dist = (float)sqrt((double)s);
    nx = dx / dist; ny = dy / dist; nz = dz / dist;
    float x = dist / 5.0f;
    float x2 = x * x, x4 = x2 * x2;
    float x5 = x4 * x, x6 = x5 * x, x7 = x6 * x;
    float env = 1.0f / x;
    env = env + (-28.0f) * x5;
    env = env + 48.0f * x6;
    env = env + (-21.0f) * x7;
#pragma unroll
    for (int l = 0; l < L_SPH; l++) {
#pragma unroll
        for (int n = 0; n < K_RAD; n++) {
            float t  = x * c.z[l][n];
            float sn, co;
            if (l == 0) { sn = sin_f32cr(t); co = 0.0f; }
            else        { sincos_f32cr(t, sn, co); }
            float j  = sn / t;
            if (l > 0) {
                float t2 = t * t;
                float a1 = sn / t2;
                float a2 = co / t;
                float jp = a1 - a2;
#pragma unroll
                for (int i = 1; i < l; i++) {
                    float q  = (float)(2 * i + 1) / t;
                    float m  = q * jp;
                    float nj = m - j;
                    j = jp; jp = nj;
                }
                j = jp;
            }
            float rb = c.nrm[l][n] * j;
            row[l * K_RAD + n] = rb * env;
        }
    }
}

__global__ __launch_bounds__(TPB) void fused_kernel(
        const float* __restrict__ d, const int* __restrict__ snd,
        const int* __restrict__ rcv, float* __restrict__ out,
        int nP, SBConsts c) {
#pragma clang fp contract(off)
    int p = blockIdx.x * TPB + threadIdx.x;
    if (p >= nP) return;
    int s = snd[p], r = rcv[p];
    float row[LK], sx, sy, sz;
    edge_row_f32(d[3 * s], d[3 * s + 1], d[3 * s + 2], c, row, sx, sy, sz);
    float rx = d[3 * r], ry = d[3 * r + 1], rz = d[3 * r + 2];
    float t = rx * rx;  t = t + ry * ry;  t = t + rz * rz;
    float rd = (float)sqrt((double)t);
    float cs = sx * (rx / rd);
    cs = cs + sy * (ry / rd);
    cs = cs + sz * (rz / rd);
    float cbf[L_SPH];
    legendre_cbf(cs, c.sphc, cbf);
    float* o = out + (size_t)p * LK;
#pragma unroll
    for (int j = 0; j < LK; j++) o[j] = row[j] * cbf[j / K_RAD];
}

// ---------------- launch -----------------------------------------------------

extern "C" void kernel_launch(void* const* d_in, const int* in_sizes, int n_in,
                              void* d_out, int out_size, void* d_ws, size_t ws_size,
                              hipStream_t stream) {
    static SBConsts c = make_consts();
    const float* dists = (const float*)d_in[0];
    const int*   snd   = (const int*)d_in[1];
    const int*   rcv   = (const int*)d_in[2];
    float*       out   = (float*)d_out;
    int nE = in_sizes[0] / 3;
    int nP = in_sizes[1];

    size_t rbf_b = (size_t)nE * RSTR * sizeof(float);   // 96 MB, 192B rows
    size_t nd4_b = (size_t)nE * sizeof(float4);         //  8 MB
    size_t tab_b = 512;                                 // 84-float LUT
    size_t need  = rbf_b + nd4_b + tab_b;

    if (ws_size >= need) {
        float*  rbf = (float*)d_ws;
        float4* nd4 = (float4*)((char*)d_ws + rbf_b);
        float*  tab = (float*)((char*)d_ws + rbf_b + nd4_b);
        init_tab  <<<1, 64, 0, stream>>>(tab, c);
        edge_fused<<<(nE + EPB - 1) / EPB, TPB, 0, stream>>>(dists, tab, rbf, nd4, nE);
        pair_kernel<<<(nP + PTPB - 1) / PTPB, PTPB, 0, stream>>>(snd, rcv, rbf, nd4, out, nP, c);
    } else {
        fused_kernel<<<(nP + TPB - 1) / TPB, TPB, 0, stream>>>(dists, snd, rcv, out, nP, c);
    }
}